// Round 15
// baseline (11094.402 us; speedup 1.0000x reference)
//
#include <hip/hip_runtime.h>

#define T_STEPS 256
#define H_DIM   1024
#define L_CTX   200
#define CTXD    512
#define A_DIM   512
#define G4      4096
#define KT2     3072   // W4T k-range: 1024 Uh + 1024 Ph + 1024 Hh
#define NBLK    64
#define NTHR    512

typedef __attribute__((ext_vector_type(8))) unsigned short us8;

// ws offsets (floats) — every per-step slot is fresh (never reused) and
// >=2KB-aligned so no cache/fetch granule spans an unwritten region.
#define OFF_XWB    0                           // 256*4096 f32
#define OFF_CTXW   (OFF_XWB   + T_STEPS*G4)    // 200*512 f32
#define OFF_HIST   (OFF_CTXW  + L_CTX*A_DIM)   // 256*1024 f32 (write-once rows)
#define OFF_UW     (OFF_HIST  + T_STEPS*H_DIM) // 256*1024 f32: per-step [u|w]
#define OFF_E      (OFF_UW    + T_STEPS*H_DIM) // 256*512  f32: per-step [eC|eH]
#define OFF_HISTW  (OFF_E     + T_STEPS*A_DIM) // 256*512  f32 (write-once rows)
#define OFF_CC     (OFF_HISTW + T_STEPS*A_DIM) // bf16 4096*200
#define OFF_HH     (OFF_CC    + G4*L_CTX/2)    // bf16 4096*256 (block-private)
#define OFF_W4T    (OFF_HH    + G4*T_STEPS/2)  // bf16 4096*3072
#define OFF_WT3    (OFF_W4T   + G4*KT2/2)      // bf16 1536*1024
#define OFF_BAR    (OFF_WT3   + 1536*H_DIM/2)  // 64 byte-flags (one 64B line)
#define WS_FLOATS  (OFF_BAR   + 256)

__device__ __forceinline__ float sigmoidf_(float x) { return 1.f / (1.f + __expf(-x)); }
__device__ __forceinline__ float bf2f(unsigned short h) { return __uint_as_float((unsigned)h << 16); }
__device__ __forceinline__ unsigned short f2bf(float x) {
    unsigned u = __float_as_uint(x);
    return (unsigned short)((u + 0x7FFFu + ((u >> 16) & 1u)) >> 16);
}
// agent-scope store: data reaches the coherence point (then read cold+cached)
__device__ __forceinline__ void st_ag(float* p, float v) {
    __hip_atomic_store(p, v, __ATOMIC_RELAXED, __HIP_MEMORY_SCOPE_AGENT);
}
__device__ __forceinline__ float wred(float x) {
    #pragma unroll
    for (int off = 32; off; off >>= 1) x += __shfl_down(x, off);
    return x;
}
__device__ __forceinline__ float wredmax(float x) {
    #pragma unroll
    for (int off = 32; off; off >>= 1) x = fmaxf(x, __shfl_down(x, off));
    return x;
}

// flag barrier: 64 byte-flags in ONE 64B line; only wave 0 polls (one 64-lane
// uncached load per round). __syncthreads() before arrival drains vmcnt so all
// prior st_ag payload is at the coherence point before the flag store.
__device__ __forceinline__ void gbar(unsigned char* bar, int b, unsigned ph) {
    __syncthreads();
    if (threadIdx.x < 64) {
        const unsigned char tgt = (unsigned char)ph;
        if (threadIdx.x == 0)
            __hip_atomic_store(bar + b, tgt, __ATOMIC_RELAXED, __HIP_MEMORY_SCOPE_AGENT);
        for (int spins = 0; spins < 40000; ++spins) {   // cap = hang insurance
            unsigned char f = __hip_atomic_load(bar + threadIdx.x, __ATOMIC_RELAXED,
                                                __HIP_MEMORY_SCOPE_AGENT);
            if (!__any((int)(signed char)(f - tgt) < 0)) break;
            __builtin_amdgcn_s_sleep(1);
        }
    }
    __syncthreads();
}

// ---------- prep kernels ----------

__global__ __launch_bounds__(256) void k_xwb(const float* __restrict__ X,
                                             const float* __restrict__ Wx,
                                             const float* __restrict__ b4,
                                             float* __restrict__ XWb) {
    int c  = blockIdx.x * 256 + threadIdx.x;
    int r0 = blockIdx.y * 8;
    float acc[8] = {0,0,0,0,0,0,0,0};
    for (int k = 0; k < 512; ++k) {
        float wv = Wx[(size_t)k * G4 + c];
        #pragma unroll
        for (int r = 0; r < 8; ++r) acc[r] += X[(r0 + r) * 512 + k] * wv;
    }
    float bb = b4[c];
    #pragma unroll
    for (int r = 0; r < 8; ++r) XWb[(size_t)(r0 + r) * G4 + c] = acc[r] + bb;
}

__global__ __launch_bounds__(256) void k_ctxw(const float* __restrict__ ctx,
                                              const float* __restrict__ Wctx,
                                              const float* __restrict__ bctx,
                                              float* __restrict__ ctxW) {
    int a  = blockIdx.x * 256 + threadIdx.x;
    int l0 = blockIdx.y * 8;
    float acc[8] = {0,0,0,0,0,0,0,0};
    for (int k = 0; k < 512; ++k) {
        float wv = Wctx[(size_t)k * A_DIM + a];
        #pragma unroll
        for (int r = 0; r < 8; ++r) acc[r] += ctx[(l0 + r) * CTXD + k] * wv;
    }
    float bb = bctx[a];
    #pragma unroll
    for (int r = 0; r < 8; ++r) ctxW[(l0 + r) * A_DIM + a] = acc[r] + bb;
}

// cc[colp][l] = ctx[l] . Cc[:,c]  (bf16 out)  grid(16,25)
__global__ __launch_bounds__(256) void k_cc(const float* __restrict__ ctx,
                                            const float* __restrict__ Cc,
                                            unsigned short* __restrict__ CCp) {
    int c  = blockIdx.x * 256 + threadIdx.x;
    int l0 = blockIdx.y * 8;
    float acc[8] = {0,0,0,0,0,0,0,0};
    for (int k = 0; k < 512; ++k) {
        float wv = Cc[(size_t)k * G4 + c];
        #pragma unroll
        for (int r = 0; r < 8; ++r) acc[r] += ctx[(l0 + r) * CTXD + k] * wv;
    }
    int colp = 4 * (c & 1023) + (c >> 10);
    #pragma unroll
    for (int r = 0; r < 8; ++r) CCp[(size_t)colp * L_CTX + l0 + r] = f2bf(acc[r]);
}

// pack [Uh;Ph;Hh] -> W4T[col=4d+q][k] bf16.  grid(96, 32, 4)
__global__ __launch_bounds__(256) void k_packW4(const float* __restrict__ Uh,
                                                const float* __restrict__ Ph,
                                                const float* __restrict__ Hh,
                                                unsigned short* __restrict__ W4T) {
    __shared__ float tile[32][33];
    const int k0 = blockIdx.x * 32, d0 = blockIdx.y * 32, q = blockIdx.z;
    const int x = threadIdx.x & 31, yy = threadIdx.x >> 5;
    const int c = q * 1024 + d0 + x;
    #pragma unroll
    for (int i = 0; i < 32; i += 8) {
        int ka = k0 + yy + i;
        const float* src; int kk;
        if (ka < 1024)      { src = Uh; kk = ka; }
        else if (ka < 2048) { src = Ph; kk = ka - 1024; }
        else                { src = Hh; kk = ka - 2048; }
        tile[yy + i][x] = src[(size_t)kk * G4 + c];
    }
    __syncthreads();
    #pragma unroll
    for (int i = 0; i < 32; i += 8) {
        int dd = yy + i;
        int col = 4 * (d0 + dd) + q;
        W4T[(size_t)col * KT2 + k0 + x] = f2bf(tile[x][dd]);
    }
}

__global__ __launch_bounds__(256) void k_packW3(const float* __restrict__ Wh,
                                                const float* __restrict__ Whh,
                                                const float* __restrict__ Whist,
                                                unsigned short* __restrict__ WT3) {
    __shared__ float tile[32][33];
    const int k0 = blockIdx.x * 32, c0 = blockIdx.y * 32, s = blockIdx.z;
    const float* S = (s == 0) ? Wh : (s == 1) ? Whh : Whist;
    const int x = threadIdx.x & 31, yy = threadIdx.x >> 5;
    #pragma unroll
    for (int i = 0; i < 32; i += 8)
        tile[yy + i][x] = S[(size_t)(k0 + yy + i) * 512 + c0 + x];
    __syncthreads();
    #pragma unroll
    for (int i = 0; i < 32; i += 8) {
        int dd = yy + i;
        WT3[(size_t)(s * 512 + c0 + dd) * H_DIM + k0 + x] = f2bf(tile[x][dd]);
    }
}

// ---------- persistent recurrent kernel (64 blocks x 512 threads) ----------

struct LP {
    const float *ctx, *c0, *v, *v2, *bv, *bv2, *bhist, *h0;
    const int* parent;
    float* ws;
    float* out;
};

__global__ __launch_bounds__(NTHR) void lstm_loop(LP p) {
    const int b    = blockIdx.x;
    const int tid  = threadIdx.x;
    const int lane = tid & 63, wv = tid >> 6;   // 8 waves

    float* XWb   = p.ws + OFF_XWB;
    float* ctxW  = p.ws + OFF_CTXW;
    float* hist  = p.ws + OFF_HIST;    // per-step rows, write-once
    float* UW    = p.ws + OFF_UW;      // per-step [u(512)|w(512)]
    float* E     = p.ws + OFF_E;       // per-step [eC(256)|eH(256)]
    float* histW = p.ws + OFF_HISTW;   // per-step rows, write-once
    const unsigned short* CCp = (const unsigned short*)(p.ws + OFF_CC);
    unsigned short*       HHp = (unsigned short*)(p.ws + OFF_HH);
    const unsigned short* W4T = (const unsigned short*)(p.ws + OFF_W4T);
    const unsigned short* WT3 = (const unsigned short*)(p.ws + OFF_WT3);
    unsigned char* bar = (unsigned char*)(p.ws + OFF_BAR);

    __shared__ float xs[2048];        // [h_prev | par]
    __shared__ float uw_[512];        // u (eC blocks) or w (eH blocks)
    __shared__ float vs_[512], v2s_[512];
    __shared__ float aC[256], aH[256];
    __shared__ float red[16], sc[4], zs[64];

    vs_[tid] = p.v[tid];  v2s_[tid] = p.v2[tid];
    // stage h0 + zero par for step 0
    xs[tid] = p.h0[tid];  xs[512 + tid] = p.h0[512 + tid];
    xs[1024 + tid] = 0.f; xs[1536 + tid] = 0.f;
    __syncthreads();

    // ---- prologue (= C for t=-1): UW[0] = [Wh^T h0 | Whh^T h0 + bhist] ----
    #pragma unroll
    for (int rr = 0; rr < 2; ++rr) {
        int j = b * 16 + wv * 2 + rr;              // [0,1024)
        const us8* wr = (const us8*)(WT3 + (size_t)j * H_DIM) + lane * 2;
        us8 a0 = wr[0], a1 = wr[1];
        float s = 0.f;
        #pragma unroll
        for (int k = 0; k < 8; ++k) s += bf2f(a0[k]) * xs[lane * 16 + k];
        #pragma unroll
        for (int k = 0; k < 8; ++k) s += bf2f(a1[k]) * xs[lane * 16 + 8 + k];
        s = wred(s);
        if (lane == 0)
            st_ag(UW + j, (j < A_DIM) ? s : s + p.bhist[j - A_DIM]);
    }
    unsigned ph = 1;
    gbar(bar, b, ph++);

    // column mapping: block owns permuted cols [b*64, b*64+64); 8 subs/col
    const int cg  = tid >> 3;          // local col [0,64)
    const int sub = tid & 7;
    const us8* Wcol = (const us8*)(W4T + (size_t)(b * 64 + cg) * KT2);
    const unsigned short* ccC = CCp + (size_t)(b * 64 + cg) * L_CTX;
    unsigned short*       hhC = HHp + (size_t)(b * 64 + cg) * T_STEPS;

    for (int t = 0; t < T_STEPS; ++t) {
        // ---------------- A: attention logits (read UW[t] COLD+CACHED) ----------------
        if (b < 25) {
            uw_[tid] = UW[(size_t)t * H_DIM + tid];          // cold cached
            __syncthreads();
            const int idx = b * 8 + wv;           // [0,200)
            if (idx < L_CTX) {
                const float4* cw = (const float4*)(ctxW + (size_t)idx * A_DIM) + lane * 2;
                float4 c0v = cw[0], c1v = cw[1];
                const int i0 = lane * 8;
                float e = tanhf(c0v.x + uw_[i0+0]) * vs_[i0+0]
                        + tanhf(c0v.y + uw_[i0+1]) * vs_[i0+1]
                        + tanhf(c0v.z + uw_[i0+2]) * vs_[i0+2]
                        + tanhf(c0v.w + uw_[i0+3]) * vs_[i0+3]
                        + tanhf(c1v.x + uw_[i0+4]) * vs_[i0+4]
                        + tanhf(c1v.y + uw_[i0+5]) * vs_[i0+5]
                        + tanhf(c1v.z + uw_[i0+6]) * vs_[i0+6]
                        + tanhf(c1v.w + uw_[i0+7]) * vs_[i0+7];
                e = wred(e);
                if (lane == 0) st_ag(E + (size_t)t * A_DIM + idx, e + p.bv[0]);
            }
        } else if (b >= 32) {
            uw_[tid] = UW[(size_t)t * H_DIM + 512 + tid];    // cold cached
            __syncthreads();
            const int j = (b - 32) * 8 + wv;      // [0,256)
            if (j < t) {
                const float4* hw4 = (const float4*)(histW + (size_t)j * A_DIM) + lane * 2;
                float4 h0v = hw4[0], h1v = hw4[1];           // cached (row immutable)
                const int i0 = lane * 8;
                float e = tanhf(h0v.x + uw_[i0+0]) * v2s_[i0+0]
                        + tanhf(h0v.y + uw_[i0+1]) * v2s_[i0+1]
                        + tanhf(h0v.z + uw_[i0+2]) * v2s_[i0+2]
                        + tanhf(h0v.w + uw_[i0+3]) * v2s_[i0+3]
                        + tanhf(h1v.x + uw_[i0+4]) * v2s_[i0+4]
                        + tanhf(h1v.y + uw_[i0+5]) * v2s_[i0+5]
                        + tanhf(h1v.z + uw_[i0+6]) * v2s_[i0+6]
                        + tanhf(h1v.w + uw_[i0+7]) * v2s_[i0+7];
                e = wred(e);
                if (lane == 0) st_ag(E + (size_t)t * A_DIM + 256 + j, e + p.bv2[0]);
            }
        }
        gbar(bar, b, ph++);  // S1

        // ---------------- B: softmax (replicated) + z + gates + outputs ----------------
        if (tid < L_CTX) aC[tid] = E[(size_t)t * A_DIM + tid];          // cold cached
        if (tid < t)     aH[tid] = E[(size_t)t * A_DIM + 256 + tid];    // cold cached
        __syncthreads();
        {
            float pC = (tid < L_CTX) ? aC[tid] : -3e38f;
            float pH = (tid < t)     ? aH[tid] : -3e38f;
            pC = wredmax(pC); pH = wredmax(pH);
            if (lane == 0) { red[wv] = pC; red[8 + wv] = pH; }
            __syncthreads();
            if (tid == 0) { float m = -3e38f; for (int g = 0; g < 8; ++g) m = fmaxf(m, red[g]); sc[0] = m; }
            if (tid == 1) { float m = -3e38f; for (int g = 0; g < 8; ++g) m = fmaxf(m, red[8 + g]); sc[1] = m; }
            __syncthreads();
            const float mC = sc[0], mH = sc[1];
            float sCp = 0.f, sHp = 0.f;
            if (tid < L_CTX) { float x = __expf(aC[tid] - mC); aC[tid] = x; sCp = x; }
            if (tid < t)     { float x = __expf(aH[tid] - mH); aH[tid] = x; sHp = x; }
            sCp = wred(sCp); sHp = wred(sHp);
            if (lane == 0) { red[wv] = sCp; red[8 + wv] = sHp; }
            __syncthreads();
            if (tid == 0) { float s = 0.f; for (int g = 0; g < 8; ++g) s += red[g]; sc[2] = s; }
            if (tid == 1) { float s = 0.f; for (int g = 0; g < 8; ++g) s += red[8 + g]; sc[3] = s; }
            __syncthreads();
            const float rC = 1.f / sc[2];
            const float rH = (t > 0) ? 1.f / sc[3] : 0.f;

            // z = GEMV(Uh,Ph over [h|par]) + attn via cc/hh
            float a0f = 0.f, a1f = 0.f;
            #pragma unroll 8
            for (int i = 0; i < 32; ++i) {
                const int c = i * 8 + sub;
                us8 w8 = Wcol[c];
                const float* xk = xs + c * 8;
                float d0 = bf2f(w8[0])*xk[0] + bf2f(w8[1])*xk[1]
                         + bf2f(w8[2])*xk[2] + bf2f(w8[3])*xk[3];
                float d1 = bf2f(w8[4])*xk[4] + bf2f(w8[5])*xk[5]
                         + bf2f(w8[6])*xk[6] + bf2f(w8[7])*xk[7];
                if (i & 1) a1f += d0 + d1; else a0f += d0 + d1;
            }
            float acc = a0f + a1f;
            float attc = 0.f, atth = 0.f;
            for (int l = sub; l < L_CTX; l += 8) attc += aC[l] * bf2f(ccC[l]);
            for (int j = sub; j < t; j += 8)     atth += aH[j] * bf2f(hhC[j]);
            acc += attc * rC + atth * rH;
            acc += __shfl_down(acc, 4, 8);
            acc += __shfl_down(acc, 2, 8);
            acc += __shfl_down(acc, 1, 8);
            if (sub == 0) zs[cg] = acc;
            __syncthreads();
            if (tid < 16) {
                const int d = b * 16 + tid;
                float zi = zs[4 * tid + 0] + XWb[(size_t)t * G4 + 0 * 1024 + d];
                float zf = zs[4 * tid + 1] + XWb[(size_t)t * G4 + 1 * 1024 + d];
                float zc = zs[4 * tid + 2] + XWb[(size_t)t * G4 + 2 * 1024 + d];
                float zo = zs[4 * tid + 3] + XWb[(size_t)t * G4 + 3 * 1024 + d];
                float cn = sigmoidf_(zf) * p.c0[d] + sigmoidf_(zi) * tanhf(zc);
                float hn = sigmoidf_(zo) * tanhf(cn);
                st_ag(hist + (size_t)t * H_DIM + d, hn);
                p.out[(size_t)t * H_DIM + d] = hn;
            }
            // ctx_vec output: dim d = b*8+wv; cached column reads of ctx
            {
                const int d = b * 8 + wv;
                float s = 0.f;
                for (int l = lane; l < L_CTX; l += 64)
                    s += aC[l] * p.ctx[(size_t)l * CTXD + d];
                s = wred(s);
                if (lane == 0)
                    p.out[(size_t)T_STEPS * H_DIM + (size_t)t * CTXD + d] = s * rC;
            }
        }
        gbar(bar, b, ph++);  // S2

        if (t == T_STEPS - 1) break;

        // ---------------- C: stage next h/par + UW[t+1] + histW[t] + hh[t] ----------------
        xs[tid]       = hist[(size_t)t * H_DIM + tid];           // cold cached (fresh row)
        xs[512 + tid] = hist[(size_t)t * H_DIM + 512 + tid];
        {
            const int ptn = p.parent[t + 1];                     // ptn <= t, rows immutable
            xs[1024 + tid] = hist[(size_t)ptn * H_DIM + tid];
            xs[1536 + tid] = hist[(size_t)ptn * H_DIM + 512 + tid];
        }
        __syncthreads();
        {
            #pragma unroll
            for (int rr = 0; rr < 3; ++rr) {
                const int j = b * 24 + wv * 3 + rr;   // [0,1536)
                const us8* wr = (const us8*)(WT3 + (size_t)j * H_DIM) + lane * 2;
                us8 a0 = wr[0], a1 = wr[1];
                float s = 0.f;
                #pragma unroll
                for (int k = 0; k < 8; ++k) s += bf2f(a0[k]) * xs[lane * 16 + k];
                #pragma unroll
                for (int k = 0; k < 8; ++k) s += bf2f(a1[k]) * xs[lane * 16 + 8 + k];
                s = wred(s);
                if (lane == 0) {
                    if (j < A_DIM)          st_ag(UW + (size_t)(t + 1) * H_DIM + j, s);
                    else if (j < 2 * A_DIM) st_ag(UW + (size_t)(t + 1) * H_DIM + j, s + p.bhist[j - A_DIM]);
                    else                    st_ag(histW + (size_t)t * A_DIM + (j - 2 * A_DIM), s);
                }
            }
            // hh[col][t] = h_t . Hh[:,col]  (block-private, plain cached store)
            float a0f = 0.f, a1f = 0.f;
            #pragma unroll 8
            for (int i = 0; i < 16; ++i) {
                const int c2 = 256 + i * 8 + sub;
                us8 w8 = Wcol[c2];
                const float* xk = xs + (c2 - 256) * 8;
                float d0 = bf2f(w8[0])*xk[0] + bf2f(w8[1])*xk[1]
                         + bf2f(w8[2])*xk[2] + bf2f(w8[3])*xk[3];
                float d1 = bf2f(w8[4])*xk[4] + bf2f(w8[5])*xk[5]
                         + bf2f(w8[6])*xk[6] + bf2f(w8[7])*xk[7];
                if (i & 1) a1f += d0 + d1; else a0f += d0 + d1;
            }
            float hv = a0f + a1f;
            hv += __shfl_down(hv, 4, 8);
            hv += __shfl_down(hv, 2, 8);
            hv += __shfl_down(hv, 1, 8);
            if (sub == 0) hhC[t] = f2bf(hv);
        }
        gbar(bar, b, ph++);  // S3
    }
}

// ---------- host ----------

extern "C" void kernel_launch(void* const* d_in, const int* in_sizes, int n_in,
                              void* d_out, int out_size, void* d_ws, size_t ws_size,
                              hipStream_t stream) {
    if (ws_size < (size_t)WS_FLOATS * sizeof(float)) return;  // OOB insurance

    const float* X      = (const float*)d_in[0];
    const float* ctx    = (const float*)d_in[1];
    const float* h0     = (const float*)d_in[2];
    const float* c0     = (const float*)d_in[3];
    const int*   parent = (const int*)  d_in[4];
    const float* Wx     = (const float*)d_in[5];
    const float* Uh     = (const float*)d_in[6];
    const float* Cc     = (const float*)d_in[7];
    const float* Ph     = (const float*)d_in[8];
    const float* Hh     = (const float*)d_in[9];
    const float* b4     = (const float*)d_in[10];
    const float* Wctx   = (const float*)d_in[11];
    const float* bctx   = (const float*)d_in[12];
    const float* Wh     = (const float*)d_in[13];
    const float* v      = (const float*)d_in[14];
    const float* bv     = (const float*)d_in[15];
    const float* Whist  = (const float*)d_in[16];
    const float* bhist  = (const float*)d_in[17];
    const float* Whh    = (const float*)d_in[18];
    const float* v2     = (const float*)d_in[19];
    const float* bv2    = (const float*)d_in[20];
    float* ws  = (float*)d_ws;
    float* out = (float*)d_out;

    // zero barrier flags every call (deterministic across graph replays)
    hipMemsetAsync((char*)d_ws + (size_t)OFF_BAR * sizeof(float), 0, 1024, stream);

    hipLaunchKernelGGL(k_xwb,    dim3(16, 32),    dim3(256), 0, stream, X,   Wx,   b4,   ws + OFF_XWB);
    hipLaunchKernelGGL(k_ctxw,   dim3(2, 25),     dim3(256), 0, stream, ctx, Wctx, bctx, ws + OFF_CTXW);
    hipLaunchKernelGGL(k_cc,     dim3(16, 25),    dim3(256), 0, stream, ctx, Cc,
                       (unsigned short*)(ws + OFF_CC));
    hipLaunchKernelGGL(k_packW4, dim3(96, 32, 4), dim3(256), 0, stream, Uh, Ph, Hh,
                       (unsigned short*)(ws + OFF_W4T));
    hipLaunchKernelGGL(k_packW3, dim3(32, 16, 3), dim3(256), 0, stream, Wh, Whh, Whist,
                       (unsigned short*)(ws + OFF_WT3));

    LP p{ctx, c0, v, v2, bv, bv2, bhist, h0, parent, ws, out};
    hipLaunchKernelGGL(lstm_loop, dim3(NBLK), dim3(NTHR), 0, stream, p);
}

// Round 16
// 7569.174 us; speedup vs baseline: 1.4657x; 1.4657x over previous
//
#include <hip/hip_runtime.h>

#define T_STEPS 256
#define H_DIM   1024
#define L_CTX   200
#define CTXD    512
#define A_DIM   512
#define G4      4096
#define KT2     3072   // W4T k-range: 1024 Uh + 1024 Ph + 1024 Hh
#define NBLK    64
#define NTHR    512

typedef __attribute__((ext_vector_type(8))) unsigned short us8;

// ws offsets (floats) — per-step slots fresh (never reused), 2KB-aligned.
#define OFF_XWB    0                           // 256*4096 f32
#define OFF_CTXW   (OFF_XWB   + T_STEPS*G4)    // 200*512 f32
#define OFF_HIST   (OFF_CTXW  + L_CTX*A_DIM)   // 256*1024 f32 (write-once rows)
#define OFF_UW     (OFF_HIST  + T_STEPS*H_DIM) // 256*1024 f32: per-step [u|w]
#define OFF_E      (OFF_UW    + T_STEPS*H_DIM) // 256*512  f32: per-step [eC|eH]
#define OFF_HISTW  (OFF_E     + T_STEPS*A_DIM) // 256*512  f32 (write-once rows)
#define OFF_CC     (OFF_HISTW + T_STEPS*A_DIM) // bf16 4096*200
#define OFF_HH     (OFF_CC    + G4*L_CTX/2)    // bf16 4096*256 (block-private)
#define OFF_W4TI8  (OFF_HH    + G4*T_STEPS/2)  // int8 4096*3072 = 3145728 fl
#define OFF_WSC    (OFF_W4TI8 + G4*KT2/4)      // 4096 f32 per-col quant step
#define OFF_WT3    (OFF_WSC   + G4)            // bf16 1536*1024
#define OFF_BAR    (OFF_WT3   + 1536*H_DIM/2)  // 64 byte-flags (one 64B line)
#define WS_FLOATS  (OFF_BAR   + 256)

__device__ __forceinline__ float sigmoidf_(float x) { return 1.f / (1.f + __expf(-x)); }
__device__ __forceinline__ float bf2f(unsigned short h) { return __uint_as_float((unsigned)h << 16); }
__device__ __forceinline__ unsigned short f2bf(float x) {
    unsigned u = __float_as_uint(x);
    return (unsigned short)((u + 0x7FFFu + ((u >> 16) & 1u)) >> 16);
}
// agent-scope store: data reaches the coherence point (then read cold+cached)
__device__ __forceinline__ void st_ag(float* p, float v) {
    __hip_atomic_store(p, v, __ATOMIC_RELAXED, __HIP_MEMORY_SCOPE_AGENT);
}
__device__ __forceinline__ float wred(float x) {
    #pragma unroll
    for (int off = 32; off; off >>= 1) x += __shfl_down(x, off);
    return x;
}
__device__ __forceinline__ float wredmax(float x) {
    #pragma unroll
    for (int off = 32; off; off >>= 1) x = fmaxf(x, __shfl_down(x, off));
    return x;
}

// flag barrier: 64 byte-flags in ONE 64B line; wave 0 polls (wraparound-safe)
__device__ __forceinline__ void gbar(unsigned char* bar, int b, unsigned ph) {
    __syncthreads();
    if (threadIdx.x < 64) {
        const unsigned char tgt = (unsigned char)ph;
        if (threadIdx.x == 0)
            __hip_atomic_store(bar + b, tgt, __ATOMIC_RELAXED, __HIP_MEMORY_SCOPE_AGENT);
        for (int spins = 0; spins < 40000; ++spins) {   // cap = hang insurance
            unsigned char f = __hip_atomic_load(bar + threadIdx.x, __ATOMIC_RELAXED,
                                                __HIP_MEMORY_SCOPE_AGENT);
            if (!__any((int)(signed char)(f - tgt) < 0)) break;
            __builtin_amdgcn_s_sleep(1);
        }
    }
    __syncthreads();
}

// ---------- prep kernels ----------

__global__ __launch_bounds__(256) void k_xwb(const float* __restrict__ X,
                                             const float* __restrict__ Wx,
                                             const float* __restrict__ b4,
                                             float* __restrict__ XWb) {
    int c  = blockIdx.x * 256 + threadIdx.x;
    int r0 = blockIdx.y * 8;
    float acc[8] = {0,0,0,0,0,0,0,0};
    for (int k = 0; k < 512; ++k) {
        float wv = Wx[(size_t)k * G4 + c];
        #pragma unroll
        for (int r = 0; r < 8; ++r) acc[r] += X[(r0 + r) * 512 + k] * wv;
    }
    float bb = b4[c];
    #pragma unroll
    for (int r = 0; r < 8; ++r) XWb[(size_t)(r0 + r) * G4 + c] = acc[r] + bb;
}

__global__ __launch_bounds__(256) void k_ctxw(const float* __restrict__ ctx,
                                              const float* __restrict__ Wctx,
                                              const float* __restrict__ bctx,
                                              float* __restrict__ ctxW) {
    int a  = blockIdx.x * 256 + threadIdx.x;
    int l0 = blockIdx.y * 8;
    float acc[8] = {0,0,0,0,0,0,0,0};
    for (int k = 0; k < 512; ++k) {
        float wv = Wctx[(size_t)k * A_DIM + a];
        #pragma unroll
        for (int r = 0; r < 8; ++r) acc[r] += ctx[(l0 + r) * CTXD + k] * wv;
    }
    float bb = bctx[a];
    #pragma unroll
    for (int r = 0; r < 8; ++r) ctxW[(l0 + r) * A_DIM + a] = acc[r] + bb;
}

// cc[colp][l] = ctx[l] . Cc[:,c]  (bf16 out)  grid(16,25)
__global__ __launch_bounds__(256) void k_cc(const float* __restrict__ ctx,
                                            const float* __restrict__ Cc,
                                            unsigned short* __restrict__ CCp) {
    int c  = blockIdx.x * 256 + threadIdx.x;
    int l0 = blockIdx.y * 8;
    float acc[8] = {0,0,0,0,0,0,0,0};
    for (int k = 0; k < 512; ++k) {
        float wv = Cc[(size_t)k * G4 + c];
        #pragma unroll
        for (int r = 0; r < 8; ++r) acc[r] += ctx[(l0 + r) * CTXD + k] * wv;
    }
    int colp = 4 * (c & 1023) + (c >> 10);
    #pragma unroll
    for (int r = 0; r < 8; ++r) CCp[(size_t)colp * L_CTX + l0 + r] = f2bf(acc[r]);
}

// per-column quant step: wsc[colp] = max|[Uh;Ph;Hh][:,c]| / 127   grid(16)
__global__ __launch_bounds__(256) void k_colmax(const float* __restrict__ Uh,
                                                const float* __restrict__ Ph,
                                                const float* __restrict__ Hh,
                                                float* __restrict__ wsc) {
    int c = blockIdx.x * 256 + threadIdx.x;   // orig col [0,4096)
    float m = 0.f;
    for (int k = 0; k < 1024; ++k) {
        m = fmaxf(m, fabsf(Uh[(size_t)k * G4 + c]));
        m = fmaxf(m, fabsf(Ph[(size_t)k * G4 + c]));
        m = fmaxf(m, fabsf(Hh[(size_t)k * G4 + c]));
    }
    int colp = 4 * (c & 1023) + (c >> 10);
    wsc[colp] = fmaxf(m, 1e-20f) / 127.f;
}

// pack [Uh;Ph;Hh] -> W4I[col=4d+q][k] int8 (per-col scale).  grid(96, 32, 4)
__global__ __launch_bounds__(256) void k_packW4i8(const float* __restrict__ Uh,
                                                  const float* __restrict__ Ph,
                                                  const float* __restrict__ Hh,
                                                  const float* __restrict__ wsc,
                                                  signed char* __restrict__ W8) {
    __shared__ float tile[32][33];
    const int k0 = blockIdx.x * 32, d0 = blockIdx.y * 32, q = blockIdx.z;
    const int x = threadIdx.x & 31, yy = threadIdx.x >> 5;
    const int c = q * 1024 + d0 + x;
    #pragma unroll
    for (int i = 0; i < 32; i += 8) {
        int ka = k0 + yy + i;
        const float* src; int kk;
        if (ka < 1024)      { src = Uh; kk = ka; }
        else if (ka < 2048) { src = Ph; kk = ka - 1024; }
        else                { src = Hh; kk = ka - 2048; }
        tile[yy + i][x] = src[(size_t)kk * G4 + c];
    }
    __syncthreads();
    #pragma unroll
    for (int i = 0; i < 32; i += 8) {
        int dd = yy + i;
        int col = 4 * (d0 + dd) + q;
        float r = 1.f / wsc[col];
        float qv = rintf(tile[x][dd] * r);
        qv = fminf(fmaxf(qv, -127.f), 127.f);
        W8[(size_t)col * KT2 + k0 + x] = (signed char)qv;
    }
}

__global__ __launch_bounds__(256) void k_packW3(const float* __restrict__ Wh,
                                                const float* __restrict__ Whh,
                                                const float* __restrict__ Whist,
                                                unsigned short* __restrict__ WT3) {
    __shared__ float tile[32][33];
    const int k0 = blockIdx.x * 32, c0 = blockIdx.y * 32, s = blockIdx.z;
    const float* S = (s == 0) ? Wh : (s == 1) ? Whh : Whist;
    const int x = threadIdx.x & 31, yy = threadIdx.x >> 5;
    #pragma unroll
    for (int i = 0; i < 32; i += 8)
        tile[yy + i][x] = S[(size_t)(k0 + yy + i) * 512 + c0 + x];
    __syncthreads();
    #pragma unroll
    for (int i = 0; i < 32; i += 8) {
        int dd = yy + i;
        WT3[(size_t)(s * 512 + c0 + dd) * H_DIM + k0 + x] = f2bf(tile[x][dd]);
    }
}

// ---------- persistent recurrent kernel (64 blocks x 512 threads) ----------

struct LP {
    const float *ctx, *c0, *v, *v2, *bv, *bv2, *bhist, *h0;
    const int* parent;
    float* ws;
    float* out;
};

__global__ __launch_bounds__(NTHR) void lstm_loop(LP p) {
    const int b    = blockIdx.x;
    const int tid  = threadIdx.x;
    const int lane = tid & 63, wv = tid >> 6;   // 8 waves

    float* XWb   = p.ws + OFF_XWB;
    float* ctxW  = p.ws + OFF_CTXW;
    float* hist  = p.ws + OFF_HIST;    // per-step rows, write-once
    float* UW    = p.ws + OFF_UW;      // per-step [u(512)|w(512)]
    float* E     = p.ws + OFF_E;       // per-step [eC(256)|eH(256)]
    float* histW = p.ws + OFF_HISTW;   // per-step rows, write-once
    const unsigned short* CCp = (const unsigned short*)(p.ws + OFF_CC);
    unsigned short*       HHp = (unsigned short*)(p.ws + OFF_HH);
    const unsigned char*  W4I = (const unsigned char*)(p.ws + OFF_W4TI8);
    const float*          WSC = p.ws + OFF_WSC;
    const unsigned short* WT3 = (const unsigned short*)(p.ws + OFF_WT3);
    unsigned char* bar = (unsigned char*)(p.ws + OFF_BAR);

    __shared__ float xs[2048];        // [h_prev | par]
    __shared__ float uw_[512];        // u (eC blocks) or w (eH blocks)
    __shared__ float vs_[512], v2s_[512];
    __shared__ float aC[256], aH[256];
    __shared__ float red[16], sc[4], zs[64];

    vs_[tid] = p.v[tid];  v2s_[tid] = p.v2[tid];
    xs[tid] = p.h0[tid];  xs[512 + tid] = p.h0[512 + tid];
    xs[1024 + tid] = 0.f; xs[1536 + tid] = 0.f;
    __syncthreads();

    // ---- prologue (= C for t=-1): UW[0] = [Wh^T h0 | Whh^T h0 + bhist] ----
    #pragma unroll
    for (int rr = 0; rr < 2; ++rr) {
        int j = b * 16 + wv * 2 + rr;              // [0,1024)
        const us8* wr = (const us8*)(WT3 + (size_t)j * H_DIM) + lane * 2;
        us8 a0 = wr[0], a1 = wr[1];
        float s = 0.f;
        #pragma unroll
        for (int k = 0; k < 8; ++k) s += bf2f(a0[k]) * xs[lane * 16 + k];
        #pragma unroll
        for (int k = 0; k < 8; ++k) s += bf2f(a1[k]) * xs[lane * 16 + 8 + k];
        s = wred(s);
        if (lane == 0)
            st_ag(UW + j, (j < A_DIM) ? s : s + p.bhist[j - A_DIM]);
    }
    unsigned ph = 1;
    gbar(bar, b, ph++);

    // column mapping: block owns permuted cols [b*64, b*64+64); 8 subs/col
    const int cg  = tid >> 3;          // local col [0,64)
    const int sub = tid & 7;
    const uint2* Wcol = (const uint2*)(W4I + (size_t)(b * 64 + cg) * KT2);
    const float  wscl = WSC[b * 64 + cg];
    const unsigned short* ccC = CCp + (size_t)(b * 64 + cg) * L_CTX;
    unsigned short*       hhC = HHp + (size_t)(b * 64 + cg) * T_STEPS;

    for (int t = 0; t < T_STEPS; ++t) {
        // ---------------- A: attention logits (read UW[t] COLD+CACHED) ----------------
        if (b < 25) {
            uw_[tid] = UW[(size_t)t * H_DIM + tid];          // cold cached
            __syncthreads();
            const int idx = b * 8 + wv;           // [0,200)
            if (idx < L_CTX) {
                const float4* cw = (const float4*)(ctxW + (size_t)idx * A_DIM) + lane * 2;
                float4 c0v = cw[0], c1v = cw[1];
                const int i0 = lane * 8;
                float e = tanhf(c0v.x + uw_[i0+0]) * vs_[i0+0]
                        + tanhf(c0v.y + uw_[i0+1]) * vs_[i0+1]
                        + tanhf(c0v.z + uw_[i0+2]) * vs_[i0+2]
                        + tanhf(c0v.w + uw_[i0+3]) * vs_[i0+3]
                        + tanhf(c1v.x + uw_[i0+4]) * vs_[i0+4]
                        + tanhf(c1v.y + uw_[i0+5]) * vs_[i0+5]
                        + tanhf(c1v.z + uw_[i0+6]) * vs_[i0+6]
                        + tanhf(c1v.w + uw_[i0+7]) * vs_[i0+7];
                e = wred(e);
                if (lane == 0) st_ag(E + (size_t)t * A_DIM + idx, e + p.bv[0]);
            }
        } else if (b >= 32) {
            uw_[tid] = UW[(size_t)t * H_DIM + 512 + tid];    // cold cached
            __syncthreads();
            const int j = (b - 32) * 8 + wv;      // [0,256)
            if (j < t) {
                const float4* hw4 = (const float4*)(histW + (size_t)j * A_DIM) + lane * 2;
                float4 h0v = hw4[0], h1v = hw4[1];           // cached (row immutable)
                const int i0 = lane * 8;
                float e = tanhf(h0v.x + uw_[i0+0]) * v2s_[i0+0]
                        + tanhf(h0v.y + uw_[i0+1]) * v2s_[i0+1]
                        + tanhf(h0v.z + uw_[i0+2]) * v2s_[i0+2]
                        + tanhf(h0v.w + uw_[i0+3]) * v2s_[i0+3]
                        + tanhf(h1v.x + uw_[i0+4]) * v2s_[i0+4]
                        + tanhf(h1v.y + uw_[i0+5]) * v2s_[i0+5]
                        + tanhf(h1v.z + uw_[i0+6]) * v2s_[i0+6]
                        + tanhf(h1v.w + uw_[i0+7]) * v2s_[i0+7];
                e = wred(e);
                if (lane == 0) st_ag(E + (size_t)t * A_DIM + 256 + j, e + p.bv2[0]);
            }
        }
        gbar(bar, b, ph++);  // S1

        // ---------------- B: softmax (replicated) + z + gates + outputs ----------------
        if (tid < L_CTX) aC[tid] = E[(size_t)t * A_DIM + tid];          // cold cached
        if (tid < t)     aH[tid] = E[(size_t)t * A_DIM + 256 + tid];    // cold cached
        __syncthreads();
        {
            float pC = (tid < L_CTX) ? aC[tid] : -3e38f;
            float pH = (tid < t)     ? aH[tid] : -3e38f;
            pC = wredmax(pC); pH = wredmax(pH);
            if (lane == 0) { red[wv] = pC; red[8 + wv] = pH; }
            __syncthreads();
            if (tid == 0) { float m = -3e38f; for (int g = 0; g < 8; ++g) m = fmaxf(m, red[g]); sc[0] = m; }
            if (tid == 1) { float m = -3e38f; for (int g = 0; g < 8; ++g) m = fmaxf(m, red[8 + g]); sc[1] = m; }
            __syncthreads();
            const float mC = sc[0], mH = sc[1];
            float sCp = 0.f, sHp = 0.f;
            if (tid < L_CTX) { float x = __expf(aC[tid] - mC); aC[tid] = x; sCp = x; }
            if (tid < t)     { float x = __expf(aH[tid] - mH); aH[tid] = x; sHp = x; }
            sCp = wred(sCp); sHp = wred(sHp);
            if (lane == 0) { red[wv] = sCp; red[8 + wv] = sHp; }
            __syncthreads();
            if (tid == 0) { float s = 0.f; for (int g = 0; g < 8; ++g) s += red[g]; sc[2] = s; }
            if (tid == 1) { float s = 0.f; for (int g = 0; g < 8; ++g) s += red[8 + g]; sc[3] = s; }
            __syncthreads();
            const float rC = 1.f / sc[2];
            const float rH = (t > 0) ? 1.f / sc[3] : 0.f;

            // z = int8-GEMV(Uh,Ph over [h|par])*scale + attn via cc/hh
            float g0 = 0.f, g1 = 0.f;
            #pragma unroll 8
            for (int i = 0; i < 32; ++i) {
                const int c = i * 8 + sub;
                uint2 w = Wcol[c];
                const float* xk = xs + c * 8;
                int wa = (int)w.x, wb = (int)w.y;
                float d0 = (float)((wa << 24) >> 24) * xk[0]
                         + (float)((wa << 16) >> 24) * xk[1]
                         + (float)((wa <<  8) >> 24) * xk[2]
                         + (float)( wa        >> 24) * xk[3];
                float d1 = (float)((wb << 24) >> 24) * xk[4]
                         + (float)((wb << 16) >> 24) * xk[5]
                         + (float)((wb <<  8) >> 24) * xk[6]
                         + (float)( wb        >> 24) * xk[7];
                if (i & 1) g1 += d0 + d1; else g0 += d0 + d1;
            }
            float acc = (g0 + g1) * wscl;
            float attc = 0.f, atth = 0.f;
            for (int l = sub; l < L_CTX; l += 8) attc += aC[l] * bf2f(ccC[l]);
            for (int j = sub; j < t; j += 8)     atth += aH[j] * bf2f(hhC[j]);
            acc += attc * rC + atth * rH;
            acc += __shfl_down(acc, 4, 8);
            acc += __shfl_down(acc, 2, 8);
            acc += __shfl_down(acc, 1, 8);
            if (sub == 0) zs[cg] = acc;
            __syncthreads();
            if (tid < 16) {
                const int d = b * 16 + tid;
                float zi = zs[4 * tid + 0] + XWb[(size_t)t * G4 + 0 * 1024 + d];
                float zf = zs[4 * tid + 1] + XWb[(size_t)t * G4 + 1 * 1024 + d];
                float zc = zs[4 * tid + 2] + XWb[(size_t)t * G4 + 2 * 1024 + d];
                float zo = zs[4 * tid + 3] + XWb[(size_t)t * G4 + 3 * 1024 + d];
                float cn = sigmoidf_(zf) * p.c0[d] + sigmoidf_(zi) * tanhf(zc);
                float hn = sigmoidf_(zo) * tanhf(cn);
                st_ag(hist + (size_t)t * H_DIM + d, hn);
                p.out[(size_t)t * H_DIM + d] = hn;
            }
            // ctx_vec output: dim d = b*8+wv; cached column reads of ctx
            {
                const int d = b * 8 + wv;
                float s = 0.f;
                for (int l = lane; l < L_CTX; l += 64)
                    s += aC[l] * p.ctx[(size_t)l * CTXD + d];
                s = wred(s);
                if (lane == 0)
                    p.out[(size_t)T_STEPS * H_DIM + (size_t)t * CTXD + d] = s * rC;
            }
        }
        gbar(bar, b, ph++);  // S2

        if (t == T_STEPS - 1) break;

        // ---------------- C: stage next h/par + UW[t+1] + histW[t] + hh[t] ----------------
        xs[tid]       = hist[(size_t)t * H_DIM + tid];           // cold cached (fresh row)
        xs[512 + tid] = hist[(size_t)t * H_DIM + 512 + tid];
        {
            const int ptn = p.parent[t + 1];                     // ptn <= t, rows immutable
            xs[1024 + tid] = hist[(size_t)ptn * H_DIM + tid];
            xs[1536 + tid] = hist[(size_t)ptn * H_DIM + 512 + tid];
        }
        __syncthreads();
        {
            #pragma unroll
            for (int rr = 0; rr < 3; ++rr) {
                const int j = b * 24 + wv * 3 + rr;   // [0,1536)
                const us8* wr = (const us8*)(WT3 + (size_t)j * H_DIM) + lane * 2;
                us8 a0 = wr[0], a1 = wr[1];
                float s = 0.f;
                #pragma unroll
                for (int k = 0; k < 8; ++k) s += bf2f(a0[k]) * xs[lane * 16 + k];
                #pragma unroll
                for (int k = 0; k < 8; ++k) s += bf2f(a1[k]) * xs[lane * 16 + 8 + k];
                s = wred(s);
                if (lane == 0) {
                    if (j < A_DIM)          st_ag(UW + (size_t)(t + 1) * H_DIM + j, s);
                    else if (j < 2 * A_DIM) st_ag(UW + (size_t)(t + 1) * H_DIM + j, s + p.bhist[j - A_DIM]);
                    else                    st_ag(histW + (size_t)t * A_DIM + (j - 2 * A_DIM), s);
                }
            }
            // hh[col][t] = h_t . Hh[:,col]  (int8 slice, block-private bf16 store)
            float g0 = 0.f, g1 = 0.f;
            #pragma unroll 8
            for (int i = 0; i < 16; ++i) {
                const int c2 = 256 + i * 8 + sub;
                uint2 w = Wcol[c2];
                const float* xk = xs + (c2 - 256) * 8;
                int wa = (int)w.x, wb = (int)w.y;
                float d0 = (float)((wa << 24) >> 24) * xk[0]
                         + (float)((wa << 16) >> 24) * xk[1]
                         + (float)((wa <<  8) >> 24) * xk[2]
                         + (float)( wa        >> 24) * xk[3];
                float d1 = (float)((wb << 24) >> 24) * xk[4]
                         + (float)((wb << 16) >> 24) * xk[5]
                         + (float)((wb <<  8) >> 24) * xk[6]
                         + (float)( wb        >> 24) * xk[7];
                if (i & 1) g1 += d0 + d1; else g0 += d0 + d1;
            }
            float hv = (g0 + g1) * wscl;
            hv += __shfl_down(hv, 4, 8);
            hv += __shfl_down(hv, 2, 8);
            hv += __shfl_down(hv, 1, 8);
            if (sub == 0) hhC[t] = f2bf(hv);
        }
        gbar(bar, b, ph++);  // S3
    }
}

// ---------- host ----------

extern "C" void kernel_launch(void* const* d_in, const int* in_sizes, int n_in,
                              void* d_out, int out_size, void* d_ws, size_t ws_size,
                              hipStream_t stream) {
    if (ws_size < (size_t)WS_FLOATS * sizeof(float)) return;  // OOB insurance

    const float* X      = (const float*)d_in[0];
    const float* ctx    = (const float*)d_in[1];
    const float* h0     = (const float*)d_in[2];
    const float* c0     = (const float*)d_in[3];
    const int*   parent = (const int*)  d_in[4];
    const float* Wx     = (const float*)d_in[5];
    const float* Uh     = (const float*)d_in[6];
    const float* Cc     = (const float*)d_in[7];
    const float* Ph     = (const float*)d_in[8];
    const float* Hh     = (const float*)d_in[9];
    const float* b4     = (const float*)d_in[10];
    const float* Wctx   = (const float*)d_in[11];
    const float* bctx   = (const float*)d_in[12];
    const float* Wh     = (const float*)d_in[13];
    const float* v      = (const float*)d_in[14];
    const float* bv     = (const float*)d_in[15];
    const float* Whist  = (const float*)d_in[16];
    const float* bhist  = (const float*)d_in[17];
    const float* Whh    = (const float*)d_in[18];
    const float* v2     = (const float*)d_in[19];
    const float* bv2    = (const float*)d_in[20];
    float* ws  = (float*)d_ws;
    float* out = (float*)d_out;

    // zero barrier flags every call (deterministic across graph replays)
    hipMemsetAsync((char*)d_ws + (size_t)OFF_BAR * sizeof(float), 0, 1024, stream);

    hipLaunchKernelGGL(k_xwb,      dim3(16, 32),    dim3(256), 0, stream, X,   Wx,   b4,   ws + OFF_XWB);
    hipLaunchKernelGGL(k_ctxw,     dim3(2, 25),     dim3(256), 0, stream, ctx, Wctx, bctx, ws + OFF_CTXW);
    hipLaunchKernelGGL(k_cc,       dim3(16, 25),    dim3(256), 0, stream, ctx, Cc,
                       (unsigned short*)(ws + OFF_CC));
    hipLaunchKernelGGL(k_colmax,   dim3(16),        dim3(256), 0, stream, Uh, Ph, Hh, ws + OFF_WSC);
    hipLaunchKernelGGL(k_packW4i8, dim3(96, 32, 4), dim3(256), 0, stream, Uh, Ph, Hh,
                       ws + OFF_WSC, (signed char*)(ws + OFF_W4TI8));
    hipLaunchKernelGGL(k_packW3,   dim3(32, 16, 3), dim3(256), 0, stream, Wh, Whh, Whist,
                       (unsigned short*)(ws + OFF_WT3));

    LP p{ctx, c0, v, v2, bv, bv2, bhist, h0, parent, ws, out};
    hipLaunchKernelGGL(lstm_loop, dim3(NBLK), dim3(NTHR), 0, stream, p);
}